// Round 3
// baseline (724.157 us; speedup 1.0000x reference)
//
#include <hip/hip_runtime.h>

// Problem constants
#define B_ 2
#define N_ 4096
#define H_ 256
#define HEADS_ 4
#define DH_ 64

typedef _Float16 f16;
typedef f16 f16x8 __attribute__((ext_vector_type(8)));
typedef f16 f16x4 __attribute__((ext_vector_type(4)));
typedef float f32x4 __attribute__((ext_vector_type(4)));

// Workspace layout (units: f16 elements)
//  h_h  : 0         2097152
//  W_h  : 2097152   4*65536 (Wq,Wk,Wv,Wo)
//  Q_h  : 2359296   2097152   (b,head,n,dh), pre-scaled by 1/8
//  K_h  : 4456448   2097152   (b,head,n,dh)
//  V_t  : 6553600   2097152   (b,head,dh,n)
//  O_h  : 8650752   2097152   (b,n,256)
//  adjb : 10747904  1048576   2 MB packed adjacency bitmask
//  p_ws : 11796480  134217728 f16 = 268 MB per-head probabilities [bh][i][j]
// big-path total = 292028416 bytes

#define HOUT_OFF 2097152  // float offset of attn part in d_out
#define PWS_OFF 11796480
#define WS_NEED 292028416ULL

__global__ __launch_bounds__(256) void cvt_kernel(
    const float* __restrict__ h, const float* __restrict__ Wq,
    const float* __restrict__ Wk, const float* __restrict__ Wv,
    const float* __restrict__ Wo, f16* __restrict__ ws) {
  int i = blockIdx.x * 256 + threadIdx.x;
  const int NH = 2097152;
  if (i < NH) {
    ws[i] = (f16)h[i];
  } else if (i < NH + 4 * 65536) {
    int j = i - NH;
    int sel = j >> 16;
    int k = j & 65535;
    const float* src = sel == 0 ? Wq : sel == 1 ? Wk : sel == 2 ? Wv : Wo;
    ws[i] = (f16)src[k];
  }
}

// Pack adj (int32 0/1, NxN) into bit-mask: adjb[row*64 + j/64] bit (j&63).
__global__ __launch_bounds__(256) void pack_adj_kernel(
    const int* __restrict__ adj, unsigned long long* __restrict__ adjb) {
  int g = blockIdx.x * 256 + threadIdx.x;
  int lane = threadIdx.x & 63;
  int av = adj[g] != 0;
  unsigned long long m = __ballot(av);
  if (lane == 0) adjb[g >> 6] = m;
}

// QKV projection. grid=(128, 12): y = wsel*4 + head. Block = 4 waves, tile 64x64.
__global__ __launch_bounds__(256) void proj_kernel(
    const f16* __restrict__ hh, const f16* __restrict__ Wh,
    const float* __restrict__ bq, const float* __restrict__ bk,
    const float* __restrict__ bv, f16* __restrict__ Qh, f16* __restrict__ Kh,
    f16* __restrict__ Vt) {
  const int tid = threadIdx.x;
  const int lane = tid & 63, w = tid >> 6;
  const int q = lane >> 4, c = lane & 15;
  const int wsel = blockIdx.y >> 2, head = blockIdx.y & 3;
  const int m0 = blockIdx.x * 64 + w * 16;
  const f16* W = Wh + wsel * 65536;
  const int o0 = head * 64;

  f32x4 acc[4] = {};
  for (int k0 = 0; k0 < 256; k0 += 32) {
    f16x8 a = *(const f16x8*)(hh + (size_t)(m0 + c) * 256 + k0 + q * 8);
#pragma unroll
    for (int cg = 0; cg < 4; ++cg) {
      f16x8 bfr = *(const f16x8*)(W + (size_t)(o0 + cg * 16 + c) * 256 + k0 + q * 8);
      acc[cg] = __builtin_amdgcn_mfma_f32_16x16x32_f16(a, bfr, acc[cg], 0, 0, 0);
    }
  }
  const int b = m0 >> 12, n = m0 & 4095;
  const float* bias = wsel == 0 ? bq : wsel == 1 ? bk : bv;
  if (wsel == 2) {
#pragma unroll
    for (int cg = 0; cg < 4; ++cg) {
      int dh = cg * 16 + c;
      float bb = bias[o0 + dh];
      f16x4 v;
#pragma unroll
      for (int r = 0; r < 4; ++r) v[r] = (f16)(acc[cg][r] + bb);
      *(f16x4*)(Vt + ((size_t)(b * HEADS_ + head) * DH_ + dh) * N_ + n + q * 4) = v;
    }
  } else {
    f16* dst = wsel == 0 ? Qh : Kh;
    const float scale = wsel == 0 ? 0.125f : 1.0f;
#pragma unroll
    for (int cg = 0; cg < 4; ++cg) {
      int dh = cg * 16 + c;
      float bb = bias[o0 + dh];
#pragma unroll
      for (int r = 0; r < 4; ++r)
        dst[((size_t)(b * HEADS_ + head) * N_ + n + q * 4 + r) * DH_ + dh] =
            (f16)((acc[cg][r] + bb) * scale);
    }
  }
}

#define TS 68  // LDS p-tile row stride (f32); rows 16B-aligned (68*4=272=17*16)
#define WTILE (16 * TS)

// ---------------- per-head attention (big-ws path) ----------------
// grid = 1024 blocks: bh = gid&7 (XCD-pinned), iblk = gid>>3 (32 rows).
// block = 512 thr = 8 waves: w = jq*2 + ih  (4 j-quarters x 2 i-groups).
// No per-iteration barriers: each wave's PV reads only its own LDS tile.
__global__ __launch_bounds__(512, 4) void attn_ph_kernel(
    const f16* __restrict__ Qh, const f16* __restrict__ Kh,
    const f16* __restrict__ Vt, const float* __restrict__ tau,
    const uint2* __restrict__ adjb, const float* __restrict__ cw,
    f16* __restrict__ Oh, f16* __restrict__ p_ws) {
  __shared__ float lds[8 * WTILE];
  __shared__ float lred[4][2][16];
  const int gid = blockIdx.x;
  const int bh = gid & 7;
  const int b = bh >> 2, h = bh & 3;
  const int i0 = (gid >> 3) * 32;
  const int tid = threadIdx.x;
  const int lane = tid & 63, w = tid >> 6;
  const int q = lane >> 4, c = lane & 15;
  const int ih = w & 1, jq = w >> 1;
  const int ibase = i0 + ih * 16;

  const f16* Qbase = Qh + ((size_t)bh * N_ + ibase + c) * DH_;
  f16x8 a0 = *(const f16x8*)(Qbase + q * 8);
  f16x8 a1 = *(const f16x8*)(Qbase + 32 + q * 8);

  const float cw_h = cw[h];  // cb cancels in softmax
  float tau_i[4];
#pragma unroll
  for (int r = 0; r < 4; ++r) tau_i[r] = tau[b * N_ + ibase + q * 4 + r];
  const f16* Kb = Kh + (size_t)bh * N_ * DH_;
  const f16* Vb = Vt + (size_t)bh * DH_ * N_;
  const float* taub = tau + b * N_;
  const int jbase = jq * 1024;

  // ---- pass 1: partial denominators over this wave's j-quarter ----
  float lsum[4] = {0.f, 0.f, 0.f, 0.f};
  for (int it = 0; it < 16; ++it) {
    const int j0 = jbase + it * 64;
    uint2 aw[4];
#pragma unroll
    for (int r = 0; r < 4; ++r)
      aw[r] = adjb[(size_t)(ibase + q * 4 + r) * 64 + (j0 >> 6)];
#pragma unroll
    for (int cg = 0; cg < 4; ++cg) {
      const f16* Kr = Kb + (size_t)(j0 + cg * 16 + c) * DH_ + q * 8;
      f16x8 k0 = *(const f16x8*)Kr;
      f16x8 k1 = *(const f16x8*)(Kr + 32);
      float tj = taub[j0 + cg * 16 + c];
      f32x4 s = {};
      s = __builtin_amdgcn_mfma_f32_16x16x32_f16(a0, k0, s, 0, 0, 0);
      s = __builtin_amdgcn_mfma_f32_16x16x32_f16(a1, k1, s, 0, 0, 0);
      const float credj = cw_h * tj;
      const unsigned shift = (cg & 1) * 16 + c;
#pragma unroll
      for (int r = 0; r < 4; ++r) {
        unsigned mword = (cg < 2) ? aw[r].x : aw[r].y;
        float e = __expf(s[r] + credj * tau_i[r]);
        lsum[r] += ((mword >> shift) & 1) ? e : 0.f;
      }
    }
  }
#pragma unroll
  for (int r = 0; r < 4; ++r) {
    float v = lsum[r];
    v += __shfl_xor(v, 1);
    v += __shfl_xor(v, 2);
    v += __shfl_xor(v, 4);
    v += __shfl_xor(v, 8);
    lsum[r] = v;
  }
  if (c == 0) {
#pragma unroll
    for (int r = 0; r < 4; ++r) lred[jq][ih][q * 4 + r] = lsum[r];
  }
  __syncthreads();
  float linv[4];
#pragma unroll
  for (int r = 0; r < 4; ++r)
    linv[r] = 1.0f / (lred[0][ih][q * 4 + r] + lred[1][ih][q * 4 + r] +
                      lred[2][ih][q * 4 + r] + lred[3][ih][q * 4 + r]);

  // ---- pass 2: p -> (LDS tile -> global f16) + PV, barrier-free ----
  f32x4 oacc[4] = {};
  float* myp = lds + w * WTILE;
  const int prow = lane >> 2, pcq = lane & 3;
  f16* pdst_base = p_ws + ((size_t)bh << 24) + (size_t)(ibase + prow) * N_ +
                   jbase + pcq * 16;
  for (int it = 0; it < 16; ++it) {
    const int j0 = jbase + it * 64;
    uint2 aw[4];
#pragma unroll
    for (int r = 0; r < 4; ++r)
      aw[r] = adjb[(size_t)(ibase + q * 4 + r) * 64 + (j0 >> 6)];
#pragma unroll
    for (int cg = 0; cg < 4; ++cg) {
      const f16* Kr = Kb + (size_t)(j0 + cg * 16 + c) * DH_ + q * 8;
      f16x8 k0 = *(const f16x8*)Kr;
      f16x8 k1 = *(const f16x8*)(Kr + 32);
      float tj = taub[j0 + cg * 16 + c];
      f32x4 s = {};
      s = __builtin_amdgcn_mfma_f32_16x16x32_f16(a0, k0, s, 0, 0, 0);
      s = __builtin_amdgcn_mfma_f32_16x16x32_f16(a1, k1, s, 0, 0, 0);
      const float credj = cw_h * tj;
      const unsigned shift = (cg & 1) * 16 + c;
#pragma unroll
      for (int r = 0; r < 4; ++r) {
        unsigned mword = (cg < 2) ? aw[r].x : aw[r].y;
        float e = __expf(s[r] + credj * tau_i[r]) * linv[r];
        myp[(q * 4 + r) * TS + cg * 16 + c] = ((mword >> shift) & 1) ? e : 0.f;
      }
    }
    // p-store: own tile -> global f16 (same-wave LDS RAW, no barrier)
    {
      const float* src = myp + prow * TS + pcq * 16;
      f32x4 s0 = *(const f32x4*)(src);
      f32x4 s1 = *(const f32x4*)(src + 4);
      f32x4 s2 = *(const f32x4*)(src + 8);
      f32x4 s3 = *(const f32x4*)(src + 12);
      f16x8 lo, hi;
#pragma unroll
      for (int t = 0; t < 4; ++t) {
        lo[t] = (f16)s0[t];
        lo[4 + t] = (f16)s1[t];
        hi[t] = (f16)s2[t];
        hi[4 + t] = (f16)s3[t];
      }
      f16* pd = pdst_base + it * 64;
      *(f16x8*)pd = lo;
      *(f16x8*)(pd + 8) = hi;
    }
    // PV: read own tile in A-fragment layout, MFMA against V_t
#pragma unroll
    for (int ks = 0; ks < 2; ++ks) {
      f32x4 plo = *(f32x4*)(myp + c * TS + ks * 32 + q * 8);
      f32x4 phi = *(f32x4*)(myp + c * TS + ks * 32 + q * 8 + 4);
      f16x8 pa;
#pragma unroll
      for (int t = 0; t < 4; ++t) {
        pa[t] = (f16)plo[t];
        pa[4 + t] = (f16)phi[t];
      }
#pragma unroll
      for (int cg = 0; cg < 4; ++cg) {
        f16x8 bfr =
            *(const f16x8*)(Vb + (size_t)(cg * 16 + c) * N_ + j0 + ks * 32 + q * 8);
        oacc[cg] = __builtin_amdgcn_mfma_f32_16x16x32_f16(pa, bfr, oacc[cg], 0, 0, 0);
      }
    }
  }
  // ---- combine PV partials across j-quarters ----
  if (jq != 0) {
#pragma unroll
    for (int cg = 0; cg < 4; ++cg)
#pragma unroll
      for (int r = 0; r < 4; ++r) myp[(cg * 4 + r) * 64 + lane] = oacc[cg][r];
  }
  __syncthreads();
  if (jq == 0) {
#pragma unroll
    for (int cg = 0; cg < 4; ++cg)
#pragma unroll
      for (int r = 0; r < 4; ++r) {
        float v = oacc[cg][r];
#pragma unroll
        for (int jj = 1; jj < 4; ++jj)
          v += lds[(jj * 2 + ih) * WTILE + (cg * 4 + r) * 64 + lane];
        Oh[((size_t)(b * N_) + ibase + q * 4 + r) * H_ + h * 64 + cg * 16 + c] =
            (f16)v;
      }
  }
}

// Head-mean of p: attn_out = 0.25 * sum_h p[bh]. 8 f32 per thread.
__global__ __launch_bounds__(256) void mean_kernel(const f16* __restrict__ p,
                                                   float* __restrict__ out) {
  size_t e = ((size_t)blockIdx.x * 256 + threadIdx.x) * 8;
  int b = (int)(e >> 24);
  size_t ij = e & 0xFFFFFF;
  const f16* base = p + ((size_t)b << 26) + ij;
  f16x8 v0 = *(const f16x8*)(base);
  f16x8 v1 = *(const f16x8*)(base + (1ull << 24));
  f16x8 v2 = *(const f16x8*)(base + (2ull << 24));
  f16x8 v3 = *(const f16x8*)(base + (3ull << 24));
  f32x4 o0, o1;
#pragma unroll
  for (int t = 0; t < 4; ++t) {
    o0[t] = ((float)v0[t] + (float)v1[t] + (float)v2[t] + (float)v3[t]) * 0.25f;
    o1[t] = ((float)v0[4 + t] + (float)v1[4 + t] + (float)v2[4 + t] +
             (float)v3[4 + t]) * 0.25f;
  }
  *(f32x4*)(out + e) = o0;
  *(f32x4*)(out + e + 4) = o1;
}

// ---------------- fused fallback (small-ws path, R2 kernel) ----------------
__global__ __launch_bounds__(512, 4) void attn_kernel(
    const f16* __restrict__ Qh, const f16* __restrict__ Kh,
    const f16* __restrict__ Vt, const float* __restrict__ tau,
    const uint2* __restrict__ adjb, const float* __restrict__ cw,
    f16* __restrict__ Oh, float* __restrict__ attn_out) {
  __shared__ float lds[8 * WTILE];
  __shared__ float lred[2][4][16];
  const int tid = threadIdx.x;
  const int lane = tid & 63, w = tid >> 6;
  const int q = lane >> 4, c = lane & 15;
  const int h = w & 3, jh = w >> 2;
  const int b = blockIdx.y;
  const int i0 = blockIdx.x * 16;

  const size_t bh = (size_t)(b * HEADS_ + h);
  const f16* Qbase = Qh + (bh * N_ + i0 + c) * DH_;
  f16x8 a0 = *(const f16x8*)(Qbase + q * 8);
  f16x8 a1 = *(const f16x8*)(Qbase + 32 + q * 8);

  const float cw_h = cw[h];
  float tau_i[4];
#pragma unroll
  for (int r = 0; r < 4; ++r) tau_i[r] = tau[b * N_ + i0 + q * 4 + r];
  const f16* Kb = Kh + bh * (size_t)N_ * DH_;
  const f16* Vb = Vt + bh * (size_t)DH_ * N_;
  const float* taub = tau + b * N_;
  const int jbase = jh * 2048;

  float lsum[4] = {0.f, 0.f, 0.f, 0.f};
  for (int it = 0; it < 32; ++it) {
    const int j0 = jbase + it * 64;
    uint2 aw[4];
#pragma unroll
    for (int r = 0; r < 4; ++r)
      aw[r] = adjb[(size_t)(i0 + q * 4 + r) * 64 + (j0 >> 6)];
#pragma unroll
    for (int cg = 0; cg < 4; ++cg) {
      const f16* Kr = Kb + (size_t)(j0 + cg * 16 + c) * DH_ + q * 8;
      f16x8 k0 = *(const f16x8*)Kr;
      f16x8 k1 = *(const f16x8*)(Kr + 32);
      float tj = taub[j0 + cg * 16 + c];
      f32x4 s = {};
      s = __builtin_amdgcn_mfma_f32_16x16x32_f16(a0, k0, s, 0, 0, 0);
      s = __builtin_amdgcn_mfma_f32_16x16x32_f16(a1, k1, s, 0, 0, 0);
      const float credj = cw_h * tj;
      const unsigned shift = (cg & 1) * 16 + c;
#pragma unroll
      for (int r = 0; r < 4; ++r) {
        unsigned mword = (cg < 2) ? aw[r].x : aw[r].y;
        float e = __expf(s[r] + credj * tau_i[r]);
        lsum[r] += ((mword >> shift) & 1) ? e : 0.f;
      }
    }
  }
#pragma unroll
  for (int r = 0; r < 4; ++r) {
    float v = lsum[r];
    v += __shfl_xor(v, 1);
    v += __shfl_xor(v, 2);
    v += __shfl_xor(v, 4);
    v += __shfl_xor(v, 8);
    lsum[r] = v;
  }
  if (c == 0) {
#pragma unroll
    for (int r = 0; r < 4; ++r) lred[jh][h][q * 4 + r] = lsum[r];
  }
  __syncthreads();
  float linv[4];
#pragma unroll
  for (int r = 0; r < 4; ++r)
    linv[r] = 1.0f / (lred[0][h][q * 4 + r] + lred[1][h][q * 4 + r]);

  f32x4 oacc[4] = {};
  float* myp = lds + w * WTILE;
  for (int it = 0; it < 32; ++it) {
    const int j0 = jbase + it * 64;
    uint2 aw[4];
#pragma unroll
    for (int r = 0; r < 4; ++r)
      aw[r] = adjb[(size_t)(i0 + q * 4 + r) * 64 + (j0 >> 6)];
#pragma unroll
    for (int cg = 0; cg < 4; ++cg) {
      const f16* Kr = Kb + (size_t)(j0 + cg * 16 + c) * DH_ + q * 8;
      f16x8 k0 = *(const f16x8*)Kr;
      f16x8 k1 = *(const f16x8*)(Kr + 32);
      float tj = taub[j0 + cg * 16 + c];
      f32x4 s = {};
      s = __builtin_amdgcn_mfma_f32_16x16x32_f16(a0, k0, s, 0, 0, 0);
      s = __builtin_amdgcn_mfma_f32_16x16x32_f16(a1, k1, s, 0, 0, 0);
      const float credj = cw_h * tj;
      const unsigned shift = (cg & 1) * 16 + c;
#pragma unroll
      for (int r = 0; r < 4; ++r) {
        unsigned mword = (cg < 2) ? aw[r].x : aw[r].y;
        float e = __expf(s[r] + credj * tau_i[r]) * linv[r];
        myp[(q * 4 + r) * TS + cg * 16 + c] = ((mword >> shift) & 1) ? e : 0.f;
      }
    }
    __syncthreads();
    {
      int jh_m = tid >> 8, rowm = (tid >> 4) & 15, colm4 = (tid & 15) * 4;
      f32x4 sum = {};
#pragma unroll
      for (int hh = 0; hh < 4; ++hh)
        sum += *(f32x4*)(lds + (jh_m * 4 + hh) * WTILE + rowm * TS + colm4);
      sum *= 0.25f;
      *(f32x4*)(attn_out + ((size_t)(b * N_) + i0 + rowm) * N_ + jh_m * 2048 +
                it * 64 + colm4) = sum;
    }
#pragma unroll
    for (int ks = 0; ks < 2; ++ks) {
      f32x4 plo = *(f32x4*)(myp + c * TS + ks * 32 + q * 8);
      f32x4 phi = *(f32x4*)(myp + c * TS + ks * 32 + q * 8 + 4);
      f16x8 pa;
#pragma unroll
      for (int t = 0; t < 4; ++t) {
        pa[t] = (f16)plo[t];
        pa[4 + t] = (f16)phi[t];
      }
#pragma unroll
      for (int cg = 0; cg < 4; ++cg) {
        f16x8 bfr =
            *(const f16x8*)(Vb + (size_t)(cg * 16 + c) * N_ + j0 + ks * 32 + q * 8);
        oacc[cg] = __builtin_amdgcn_mfma_f32_16x16x32_f16(pa, bfr, oacc[cg], 0, 0, 0);
      }
    }
    __syncthreads();
  }
  if (jh == 1) {
#pragma unroll
    for (int cg = 0; cg < 4; ++cg)
#pragma unroll
      for (int r = 0; r < 4; ++r) myp[(cg * 4 + r) * 64 + lane] = oacc[cg][r];
  }
  __syncthreads();
  if (jh == 0) {
    const float* pp = lds + (4 + h) * WTILE;
#pragma unroll
    for (int cg = 0; cg < 4; ++cg)
#pragma unroll
      for (int r = 0; r < 4; ++r) {
        float v = oacc[cg][r] + pp[(cg * 4 + r) * 64 + lane];
        Oh[((size_t)(b * N_) + i0 + q * 4 + r) * H_ + h * 64 + cg * 16 + c] = (f16)v;
      }
  }
}

// Output projection: h_out = O @ Wo^T + bo. grid=(128,4), block=4 waves, 64x64 tile.
__global__ __launch_bounds__(256) void oproj_kernel(
    const f16* __restrict__ Oh, const f16* __restrict__ Woh,
    const float* __restrict__ bo, float* __restrict__ out) {
  const int tid = threadIdx.x, lane = tid & 63, w = tid >> 6;
  const int q = lane >> 4, c = lane & 15;
  const int m0 = blockIdx.x * 64 + w * 16;
  const int o0 = blockIdx.y * 64;
  f32x4 acc[4] = {};
  for (int k0 = 0; k0 < 256; k0 += 32) {
    f16x8 a = *(const f16x8*)(Oh + (size_t)(m0 + c) * 256 + k0 + q * 8);
#pragma unroll
    for (int cg = 0; cg < 4; ++cg) {
      f16x8 bfr = *(const f16x8*)(Woh + (size_t)(o0 + cg * 16 + c) * 256 + k0 + q * 8);
      acc[cg] = __builtin_amdgcn_mfma_f32_16x16x32_f16(a, bfr, acc[cg], 0, 0, 0);
    }
  }
#pragma unroll
  for (int cg = 0; cg < 4; ++cg) {
    float bb = bo[o0 + cg * 16 + c];
#pragma unroll
    for (int r = 0; r < 4; ++r)
      out[(size_t)(m0 + q * 4 + r) * 256 + o0 + cg * 16 + c] = acc[cg][r] + bb;
  }
}

extern "C" void kernel_launch(void* const* d_in, const int* in_sizes, int n_in,
                              void* d_out, int out_size, void* d_ws,
                              size_t ws_size, hipStream_t stream) {
  const float* h   = (const float*)d_in[0];
  const float* tau = (const float*)d_in[1];
  const int*   adj = (const int*)d_in[2];
  const float* Wq  = (const float*)d_in[3];
  const float* bq  = (const float*)d_in[4];
  const float* Wk  = (const float*)d_in[5];
  const float* bk  = (const float*)d_in[6];
  const float* Wv  = (const float*)d_in[7];
  const float* bv  = (const float*)d_in[8];
  const float* cw  = (const float*)d_in[9];
  const float* Wo  = (const float*)d_in[11];
  const float* bo  = (const float*)d_in[12];
  float* out = (float*)d_out;

  f16* ws   = (f16*)d_ws;
  f16* h_h  = ws;
  f16* W_h  = ws + 2097152;
  f16* Wo_h = W_h + 3 * 65536;
  f16* Q_h  = ws + 2359296;
  f16* K_h  = ws + 4456448;
  f16* V_t  = ws + 6553600;
  f16* O_h  = ws + 8650752;
  unsigned long long* adjb = (unsigned long long*)(ws + 10747904);
  f16* p_ws = ws + PWS_OFF;

  pack_adj_kernel<<<dim3(65536), dim3(256), 0, stream>>>(adj, adjb);
  cvt_kernel<<<dim3(9216), dim3(256), 0, stream>>>(h, Wq, Wk, Wv, Wo, ws);
  proj_kernel<<<dim3(128, 12), dim3(256), 0, stream>>>(h_h, W_h, bq, bk, bv, Q_h,
                                                       K_h, V_t);
  if (ws_size >= WS_NEED) {
    attn_ph_kernel<<<dim3(1024), dim3(512), 0, stream>>>(
        Q_h, K_h, V_t, tau, (const uint2*)adjb, cw, O_h, p_ws);
    mean_kernel<<<dim3(16384), dim3(256), 0, stream>>>(p_ws, out + HOUT_OFF);
  } else {
    attn_kernel<<<dim3(256, 2), dim3(512), 0, stream>>>(
        Q_h, K_h, V_t, tau, (const uint2*)adjb, cw, O_h, out + HOUT_OFF);
  }
  oproj_kernel<<<dim3(128, 4), dim3(256), 0, stream>>>(O_h, Wo_h, bo, out);
}

// Round 4
// 598.101 us; speedup vs baseline: 1.2108x; 1.2108x over previous
//
#include <hip/hip_runtime.h>

// Problem constants
#define B_ 2
#define N_ 4096
#define H_ 256
#define HEADS_ 4
#define DH_ 64

typedef _Float16 f16;
typedef f16 f16x8 __attribute__((ext_vector_type(8)));
typedef f16 f16x4 __attribute__((ext_vector_type(4)));
typedef float f32x4 __attribute__((ext_vector_type(4)));

// Workspace layout (units: f16 elements)
//  h_h  : 0         2097152   (dead after proj; rsum_ws f32 reuses this region)
//  W_h  : 2097152   4*65536 (Wq,Wk,Wv,Wo)
//  Q_h  : 2359296   2097152   (b,head,n,dh), pre-scaled by 1/8
//  K_h  : 4456448   2097152   (b,head,n,dh)
//  V_t  : 6553600   2097152   (b,head,dh,n)
//  O_h  : 8650752   2097152   (b,n,256)
//  adjb : 10747904  1048576   2 MB packed adjacency bitmask
//  p_ws : 11796480  134217728 f16 = 268 MB per-head UNNORMALIZED e [bh][i][j]
// big-path total = 292028416 bytes

#define HOUT_OFF 2097152  // float offset of attn part in d_out
#define PWS_OFF 11796480
#define WS_NEED 292028416ULL

__global__ __launch_bounds__(256) void cvt_kernel(
    const float* __restrict__ h, const float* __restrict__ Wq,
    const float* __restrict__ Wk, const float* __restrict__ Wv,
    const float* __restrict__ Wo, f16* __restrict__ ws) {
  int i = blockIdx.x * 256 + threadIdx.x;
  const int NH = 2097152;
  if (i < NH) {
    ws[i] = (f16)h[i];
  } else if (i < NH + 4 * 65536) {
    int j = i - NH;
    int sel = j >> 16;
    int k = j & 65535;
    const float* src = sel == 0 ? Wq : sel == 1 ? Wk : sel == 2 ? Wv : Wo;
    ws[i] = (f16)src[k];
  }
}

// Pack adj (int32 0/1, NxN) into bit-mask: adjb[row*64 + j/64] bit (j&63).
__global__ __launch_bounds__(256) void pack_adj_kernel(
    const int* __restrict__ adj, unsigned long long* __restrict__ adjb) {
  int g = blockIdx.x * 256 + threadIdx.x;
  int lane = threadIdx.x & 63;
  int av = adj[g] != 0;
  unsigned long long m = __ballot(av);
  if (lane == 0) adjb[g >> 6] = m;
}

// QKV projection. grid=(128, 12): y = wsel*4 + head. Block = 4 waves, tile 64x64.
__global__ __launch_bounds__(256) void proj_kernel(
    const f16* __restrict__ hh, const f16* __restrict__ Wh,
    const float* __restrict__ bq, const float* __restrict__ bk,
    const float* __restrict__ bv, f16* __restrict__ Qh, f16* __restrict__ Kh,
    f16* __restrict__ Vt) {
  const int tid = threadIdx.x;
  const int lane = tid & 63, w = tid >> 6;
  const int q = lane >> 4, c = lane & 15;
  const int wsel = blockIdx.y >> 2, head = blockIdx.y & 3;
  const int m0 = blockIdx.x * 64 + w * 16;
  const f16* W = Wh + wsel * 65536;
  const int o0 = head * 64;

  f32x4 acc[4] = {};
  for (int k0 = 0; k0 < 256; k0 += 32) {
    f16x8 a = *(const f16x8*)(hh + (size_t)(m0 + c) * 256 + k0 + q * 8);
#pragma unroll
    for (int cg = 0; cg < 4; ++cg) {
      f16x8 bfr = *(const f16x8*)(W + (size_t)(o0 + cg * 16 + c) * 256 + k0 + q * 8);
      acc[cg] = __builtin_amdgcn_mfma_f32_16x16x32_f16(a, bfr, acc[cg], 0, 0, 0);
    }
  }
  const int b = m0 >> 12, n = m0 & 4095;
  const float* bias = wsel == 0 ? bq : wsel == 1 ? bk : bv;
  if (wsel == 2) {
#pragma unroll
    for (int cg = 0; cg < 4; ++cg) {
      int dh = cg * 16 + c;
      float bb = bias[o0 + dh];
      f16x4 v;
#pragma unroll
      for (int r = 0; r < 4; ++r) v[r] = (f16)(acc[cg][r] + bb);
      *(f16x4*)(Vt + ((size_t)(b * HEADS_ + head) * DH_ + dh) * N_ + n + q * 4) = v;
    }
  } else {
    f16* dst = wsel == 0 ? Qh : Kh;
    const float scale = wsel == 0 ? 0.125f : 1.0f;
#pragma unroll
    for (int cg = 0; cg < 4; ++cg) {
      int dh = cg * 16 + c;
      float bb = bias[o0 + dh];
#pragma unroll
      for (int r = 0; r < 4; ++r)
        dst[((size_t)(b * HEADS_ + head) * N_ + n + q * 4 + r) * DH_ + dh] =
            (f16)((acc[cg][r] + bb) * scale);
    }
  }
}

#define TS 68  // LDS p-tile row stride (f32); rows 16B-aligned (68*4=272=17*16)
#define WTILE (16 * TS)

// ---------------- single-pass per-head attention (big-ws path) ----------------
// grid = 2048 blocks: bh = gid&7 (XCD-pinned), i-block = gid>>3 (16 rows).
// block = 256 thr = 4 waves = 4 j-quarters. No per-iteration barriers.
// Writes UNNORMALIZED e to p_ws; O scaled by linv post-loop; linv -> rsum_ws.
__global__ __launch_bounds__(256, 3) void attn_ph_kernel(
    const f16* __restrict__ Qh, const f16* __restrict__ Kh,
    const f16* __restrict__ Vt, const float* __restrict__ tau,
    const uint2* __restrict__ adjb, const float* __restrict__ cw,
    f16* __restrict__ Oh, f16* __restrict__ p_ws, float* __restrict__ rsum_ws) {
  __shared__ float lds[4 * WTILE];
  __shared__ float lred[4][16];
  const int gid = blockIdx.x;
  const int bh = gid & 7;
  const int b = bh >> 2, h = bh & 3;
  const int i0 = (gid >> 3) * 16;
  const int tid = threadIdx.x;
  const int lane = tid & 63, jq = tid >> 6;
  const int q = lane >> 4, c = lane & 15;

  const f16* Qbase = Qh + ((size_t)bh * N_ + i0 + c) * DH_;
  f16x8 a0 = *(const f16x8*)(Qbase + q * 8);
  f16x8 a1 = *(const f16x8*)(Qbase + 32 + q * 8);

  const float cw_h = cw[h];  // cb cancels in softmax
  float tau_i[4];
#pragma unroll
  for (int r = 0; r < 4; ++r) tau_i[r] = tau[b * N_ + i0 + q * 4 + r];
  const f16* Kb = Kh + (size_t)bh * N_ * DH_;
  const f16* Vb = Vt + (size_t)bh * DH_ * N_;
  const float* taub = tau + b * N_;
  const int jbase = jq * 1024;

  float lsum[4] = {0.f, 0.f, 0.f, 0.f};
  f32x4 oacc[4] = {};
  float* myp = lds + jq * WTILE;
  const int prow = lane >> 2, pcq = lane & 3;
  f16* pdst_base = p_ws + ((size_t)bh << 24) + (size_t)(i0 + prow) * N_ +
                   jbase + pcq * 16;

  for (int it = 0; it < 16; ++it) {
    const int j0 = jbase + it * 64;
    // ==== issue ALL of this iteration's loads up front (24 vmem ops) ====
    f16x8 kf[8], vf[8];
    uint2 aw[4];
    float tj[4];
#pragma unroll
    for (int cg = 0; cg < 4; ++cg) {
      const f16* Kr = Kb + (size_t)(j0 + cg * 16 + c) * DH_ + q * 8;
      kf[2 * cg] = *(const f16x8*)Kr;
      kf[2 * cg + 1] = *(const f16x8*)(Kr + 32);
    }
#pragma unroll
    for (int ks = 0; ks < 2; ++ks)
#pragma unroll
      for (int cg = 0; cg < 4; ++cg)
        vf[ks * 4 + cg] =
            *(const f16x8*)(Vb + (size_t)(cg * 16 + c) * N_ + j0 + ks * 32 + q * 8);
#pragma unroll
    for (int r = 0; r < 4; ++r)
      aw[r] = adjb[(size_t)(i0 + q * 4 + r) * 64 + (j0 >> 6)];
#pragma unroll
    for (int cg = 0; cg < 4; ++cg) tj[cg] = taub[j0 + cg * 16 + c];

    // ==== QK^T -> e = mask*exp(s) -> LDS tile (+ row-sum accumulate) ====
#pragma unroll
    for (int cg = 0; cg < 4; ++cg) {
      f32x4 s = {};
      s = __builtin_amdgcn_mfma_f32_16x16x32_f16(a0, kf[2 * cg], s, 0, 0, 0);
      s = __builtin_amdgcn_mfma_f32_16x16x32_f16(a1, kf[2 * cg + 1], s, 0, 0, 0);
      const float credj = cw_h * tj[cg];
      const unsigned shift = (cg & 1) * 16 + c;
#pragma unroll
      for (int r = 0; r < 4; ++r) {
        unsigned mword = (cg < 2) ? aw[r].x : aw[r].y;
        float e = __expf(s[r] + credj * tau_i[r]);
        e = ((mword >> shift) & 1) ? e : 0.f;
        lsum[r] += e;
        myp[(q * 4 + r) * TS + cg * 16 + c] = e;
      }
    }
    // ==== e-store: own tile -> global f16 (same-wave LDS RAW, no barrier) ====
    {
      const float* src = myp + prow * TS + pcq * 16;
      f32x4 s0 = *(const f32x4*)(src);
      f32x4 s1 = *(const f32x4*)(src + 4);
      f32x4 s2 = *(const f32x4*)(src + 8);
      f32x4 s3 = *(const f32x4*)(src + 12);
      f16x8 lo, hi;
#pragma unroll
      for (int t = 0; t < 4; ++t) {
        lo[t] = (f16)s0[t];
        lo[4 + t] = (f16)s1[t];
        hi[t] = (f16)s2[t];
        hi[4 + t] = (f16)s3[t];
      }
      f16* pd = pdst_base + it * 64;
      *(f16x8*)pd = lo;
      *(f16x8*)(pd + 8) = hi;
    }
    // ==== PV with unnormalized e (A-fragment from own LDS tile) ====
#pragma unroll
    for (int ks = 0; ks < 2; ++ks) {
      f32x4 plo = *(f32x4*)(myp + c * TS + ks * 32 + q * 8);
      f32x4 phi = *(f32x4*)(myp + c * TS + ks * 32 + q * 8 + 4);
      f16x8 pa;
#pragma unroll
      for (int t = 0; t < 4; ++t) {
        pa[t] = (f16)plo[t];
        pa[4 + t] = (f16)phi[t];
      }
#pragma unroll
      for (int cg = 0; cg < 4; ++cg)
        oacc[cg] =
            __builtin_amdgcn_mfma_f32_16x16x32_f16(pa, vf[ks * 4 + cg], oacc[cg], 0, 0, 0);
    }
  }

  // ---- combine row sums across j-quarters -> linv ----
#pragma unroll
  for (int r = 0; r < 4; ++r) {
    float v = lsum[r];
    v += __shfl_xor(v, 1);
    v += __shfl_xor(v, 2);
    v += __shfl_xor(v, 4);
    v += __shfl_xor(v, 8);
    lsum[r] = v;
  }
  if (c == 0) {
#pragma unroll
    for (int r = 0; r < 4; ++r) lred[jq][q * 4 + r] = lsum[r];
  }
  __syncthreads();
  float linv[4];
#pragma unroll
  for (int r = 0; r < 4; ++r)
    linv[r] = 1.0f / (lred[0][q * 4 + r] + lred[1][q * 4 + r] +
                      lred[2][q * 4 + r] + lred[3][q * 4 + r]);
  if (jq == 0 && c == 0) {
#pragma unroll
    for (int r = 0; r < 4; ++r) rsum_ws[bh * N_ + i0 + q * 4 + r] = linv[r];
  }

  // ---- combine PV partials across j-quarters, scale, write O ----
  if (jq != 0) {
#pragma unroll
    for (int cg = 0; cg < 4; ++cg)
#pragma unroll
      for (int r = 0; r < 4; ++r) myp[(cg * 4 + r) * 64 + lane] = oacc[cg][r];
  }
  __syncthreads();
  if (jq == 0) {
#pragma unroll
    for (int cg = 0; cg < 4; ++cg)
#pragma unroll
      for (int r = 0; r < 4; ++r) {
        float v = oacc[cg][r];
#pragma unroll
        for (int jj = 1; jj < 4; ++jj)
          v += lds[jj * WTILE + (cg * 4 + r) * 64 + lane];
        Oh[((size_t)(b * N_) + i0 + q * 4 + r) * H_ + h * 64 + cg * 16 + c] =
            (f16)(v * linv[r]);
      }
  }
}

// Head-mean: attn_out = 0.25 * sum_h e[bh]*linv[bh][i]. 8 f32 per thread.
__global__ __launch_bounds__(256) void mean_kernel(const f16* __restrict__ p,
                                                   const float* __restrict__ rsum,
                                                   float* __restrict__ out) {
  size_t e = ((size_t)blockIdx.x * 256 + threadIdx.x) * 8;
  int b = (int)(e >> 24);
  size_t ij = e & 0xFFFFFF;
  int i = (int)(ij >> 12);
  const f16* base = p + ((size_t)b << 26) + ij;
  f16x8 v0 = *(const f16x8*)(base);
  f16x8 v1 = *(const f16x8*)(base + (1ull << 24));
  f16x8 v2 = *(const f16x8*)(base + (2ull << 24));
  f16x8 v3 = *(const f16x8*)(base + (3ull << 24));
  const float l0 = rsum[(b * 4 + 0) * N_ + i] * 0.25f;
  const float l1 = rsum[(b * 4 + 1) * N_ + i] * 0.25f;
  const float l2 = rsum[(b * 4 + 2) * N_ + i] * 0.25f;
  const float l3 = rsum[(b * 4 + 3) * N_ + i] * 0.25f;
  f32x4 o0, o1;
#pragma unroll
  for (int t = 0; t < 4; ++t) {
    o0[t] = (float)v0[t] * l0 + (float)v1[t] * l1 + (float)v2[t] * l2 +
            (float)v3[t] * l3;
    o1[t] = (float)v0[4 + t] * l0 + (float)v1[4 + t] * l1 +
            (float)v2[4 + t] * l2 + (float)v3[4 + t] * l3;
  }
  *(f32x4*)(out + e) = o0;
  *(f32x4*)(out + e + 4) = o1;
}

// ---------------- fused fallback (small-ws path, R2 kernel) ----------------
__global__ __launch_bounds__(512, 4) void attn_kernel(
    const f16* __restrict__ Qh, const f16* __restrict__ Kh,
    const f16* __restrict__ Vt, const float* __restrict__ tau,
    const uint2* __restrict__ adjb, const float* __restrict__ cw,
    f16* __restrict__ Oh, float* __restrict__ attn_out) {
  __shared__ float lds[8 * WTILE];
  __shared__ float lred[2][4][16];
  const int tid = threadIdx.x;
  const int lane = tid & 63, w = tid >> 6;
  const int q = lane >> 4, c = lane & 15;
  const int h = w & 3, jh = w >> 2;
  const int b = blockIdx.y;
  const int i0 = blockIdx.x * 16;

  const size_t bh = (size_t)(b * HEADS_ + h);
  const f16* Qbase = Qh + (bh * N_ + i0 + c) * DH_;
  f16x8 a0 = *(const f16x8*)(Qbase + q * 8);
  f16x8 a1 = *(const f16x8*)(Qbase + 32 + q * 8);

  const float cw_h = cw[h];
  float tau_i[4];
#pragma unroll
  for (int r = 0; r < 4; ++r) tau_i[r] = tau[b * N_ + i0 + q * 4 + r];
  const f16* Kb = Kh + bh * (size_t)N_ * DH_;
  const f16* Vb = Vt + bh * (size_t)DH_ * N_;
  const float* taub = tau + b * N_;
  const int jbase = jh * 2048;

  float lsum[4] = {0.f, 0.f, 0.f, 0.f};
  for (int it = 0; it < 32; ++it) {
    const int j0 = jbase + it * 64;
    uint2 aw[4];
#pragma unroll
    for (int r = 0; r < 4; ++r)
      aw[r] = adjb[(size_t)(i0 + q * 4 + r) * 64 + (j0 >> 6)];
#pragma unroll
    for (int cg = 0; cg < 4; ++cg) {
      const f16* Kr = Kb + (size_t)(j0 + cg * 16 + c) * DH_ + q * 8;
      f16x8 k0 = *(const f16x8*)Kr;
      f16x8 k1 = *(const f16x8*)(Kr + 32);
      float tj = taub[j0 + cg * 16 + c];
      f32x4 s = {};
      s = __builtin_amdgcn_mfma_f32_16x16x32_f16(a0, k0, s, 0, 0, 0);
      s = __builtin_amdgcn_mfma_f32_16x16x32_f16(a1, k1, s, 0, 0, 0);
      const float credj = cw_h * tj;
      const unsigned shift = (cg & 1) * 16 + c;
#pragma unroll
      for (int r = 0; r < 4; ++r) {
        unsigned mword = (cg < 2) ? aw[r].x : aw[r].y;
        float e = __expf(s[r] + credj * tau_i[r]);
        lsum[r] += ((mword >> shift) & 1) ? e : 0.f;
      }
    }
  }
#pragma unroll
  for (int r = 0; r < 4; ++r) {
    float v = lsum[r];
    v += __shfl_xor(v, 1);
    v += __shfl_xor(v, 2);
    v += __shfl_xor(v, 4);
    v += __shfl_xor(v, 8);
    lsum[r] = v;
  }
  if (c == 0) {
#pragma unroll
    for (int r = 0; r < 4; ++r) lred[jh][h][q * 4 + r] = lsum[r];
  }
  __syncthreads();
  float linv[4];
#pragma unroll
  for (int r = 0; r < 4; ++r)
    linv[r] = 1.0f / (lred[0][h][q * 4 + r] + lred[1][h][q * 4 + r]);

  f32x4 oacc[4] = {};
  float* myp = lds + w * WTILE;
  for (int it = 0; it < 32; ++it) {
    const int j0 = jbase + it * 64;
    uint2 aw[4];
#pragma unroll
    for (int r = 0; r < 4; ++r)
      aw[r] = adjb[(size_t)(i0 + q * 4 + r) * 64 + (j0 >> 6)];
#pragma unroll
    for (int cg = 0; cg < 4; ++cg) {
      const f16* Kr = Kb + (size_t)(j0 + cg * 16 + c) * DH_ + q * 8;
      f16x8 k0 = *(const f16x8*)Kr;
      f16x8 k1 = *(const f16x8*)(Kr + 32);
      float tj = taub[j0 + cg * 16 + c];
      f32x4 s = {};
      s = __builtin_amdgcn_mfma_f32_16x16x32_f16(a0, k0, s, 0, 0, 0);
      s = __builtin_amdgcn_mfma_f32_16x16x32_f16(a1, k1, s, 0, 0, 0);
      const float credj = cw_h * tj;
      const unsigned shift = (cg & 1) * 16 + c;
#pragma unroll
      for (int r = 0; r < 4; ++r) {
        unsigned mword = (cg < 2) ? aw[r].x : aw[r].y;
        float e = __expf(s[r] + credj * tau_i[r]) * linv[r];
        myp[(q * 4 + r) * TS + cg * 16 + c] = ((mword >> shift) & 1) ? e : 0.f;
      }
    }
    __syncthreads();
    {
      int jh_m = tid >> 8, rowm = (tid >> 4) & 15, colm4 = (tid & 15) * 4;
      f32x4 sum = {};
#pragma unroll
      for (int hh = 0; hh < 4; ++hh)
        sum += *(f32x4*)(lds + (jh_m * 4 + hh) * WTILE + rowm * TS + colm4);
      sum *= 0.25f;
      *(f32x4*)(attn_out + ((size_t)(b * N_) + i0 + rowm) * N_ + jh_m * 2048 +
                it * 64 + colm4) = sum;
    }
#pragma unroll
    for (int ks = 0; ks < 2; ++ks) {
      f32x4 plo = *(f32x4*)(myp + c * TS + ks * 32 + q * 8);
      f32x4 phi = *(f32x4*)(myp + c * TS + ks * 32 + q * 8 + 4);
      f16x8 pa;
#pragma unroll
      for (int t = 0; t < 4; ++t) {
        pa[t] = (f16)plo[t];
        pa[4 + t] = (f16)phi[t];
      }
#pragma unroll
      for (int cg = 0; cg < 4; ++cg) {
        f16x8 bfr =
            *(const f16x8*)(Vb + (size_t)(cg * 16 + c) * N_ + j0 + ks * 32 + q * 8);
        oacc[cg] = __builtin_amdgcn_mfma_f32_16x16x32_f16(pa, bfr, oacc[cg], 0, 0, 0);
      }
    }
    __syncthreads();
  }
  if (jh == 1) {
#pragma unroll
    for (int cg = 0; cg < 4; ++cg)
#pragma unroll
      for (int r = 0; r < 4; ++r) myp[(cg * 4 + r) * 64 + lane] = oacc[cg][r];
  }
  __syncthreads();
  if (jh == 0) {
    const float* pp = lds + (4 + h) * WTILE;
#pragma unroll
    for (int cg = 0; cg < 4; ++cg)
#pragma unroll
      for (int r = 0; r < 4; ++r) {
        float v = oacc[cg][r] + pp[(cg * 4 + r) * 64 + lane];
        Oh[((size_t)(b * N_) + i0 + q * 4 + r) * H_ + h * 64 + cg * 16 + c] = (f16)v;
      }
  }
}

// Output projection: h_out = O @ Wo^T + bo. grid=(128,4), block=4 waves, 64x64 tile.
__global__ __launch_bounds__(256) void oproj_kernel(
    const f16* __restrict__ Oh, const f16* __restrict__ Woh,
    const float* __restrict__ bo, float* __restrict__ out) {
  const int tid = threadIdx.x, lane = tid & 63, w = tid >> 6;
  const int q = lane >> 4, c = lane & 15;
  const int m0 = blockIdx.x * 64 + w * 16;
  const int o0 = blockIdx.y * 64;
  f32x4 acc[4] = {};
  for (int k0 = 0; k0 < 256; k0 += 32) {
    f16x8 a = *(const f16x8*)(Oh + (size_t)(m0 + c) * 256 + k0 + q * 8);
#pragma unroll
    for (int cg = 0; cg < 4; ++cg) {
      f16x8 bfr = *(const f16x8*)(Woh + (size_t)(o0 + cg * 16 + c) * 256 + k0 + q * 8);
      acc[cg] = __builtin_amdgcn_mfma_f32_16x16x32_f16(a, bfr, acc[cg], 0, 0, 0);
    }
  }
#pragma unroll
  for (int cg = 0; cg < 4; ++cg) {
    float bb = bo[o0 + cg * 16 + c];
#pragma unroll
    for (int r = 0; r < 4; ++r)
      out[(size_t)(m0 + q * 4 + r) * 256 + o0 + cg * 16 + c] = acc[cg][r] + bb;
  }
}

extern "C" void kernel_launch(void* const* d_in, const int* in_sizes, int n_in,
                              void* d_out, int out_size, void* d_ws,
                              size_t ws_size, hipStream_t stream) {
  const float* h   = (const float*)d_in[0];
  const float* tau = (const float*)d_in[1];
  const int*   adj = (const int*)d_in[2];
  const float* Wq  = (const float*)d_in[3];
  const float* bq  = (const float*)d_in[4];
  const float* Wk  = (const float*)d_in[5];
  const float* bk  = (const float*)d_in[6];
  const float* Wv  = (const float*)d_in[7];
  const float* bv  = (const float*)d_in[8];
  const float* cw  = (const float*)d_in[9];
  const float* Wo  = (const float*)d_in[11];
  const float* bo  = (const float*)d_in[12];
  float* out = (float*)d_out;

  f16* ws   = (f16*)d_ws;
  f16* h_h  = ws;
  f16* W_h  = ws + 2097152;
  f16* Wo_h = W_h + 3 * 65536;
  f16* Q_h  = ws + 2359296;
  f16* K_h  = ws + 4456448;
  f16* V_t  = ws + 6553600;
  f16* O_h  = ws + 8650752;
  unsigned long long* adjb = (unsigned long long*)(ws + 10747904);
  f16* p_ws = ws + PWS_OFF;
  float* rsum_ws = (float*)ws;  // reuses dead h_h region (proj runs before attn)

  pack_adj_kernel<<<dim3(65536), dim3(256), 0, stream>>>(adj, adjb);
  cvt_kernel<<<dim3(9216), dim3(256), 0, stream>>>(h, Wq, Wk, Wv, Wo, ws);
  proj_kernel<<<dim3(128, 12), dim3(256), 0, stream>>>(h_h, W_h, bq, bk, bv, Q_h,
                                                       K_h, V_t);
  if (ws_size >= WS_NEED) {
    attn_ph_kernel<<<dim3(2048), dim3(256), 0, stream>>>(
        Q_h, K_h, V_t, tau, (const uint2*)adjb, cw, O_h, p_ws, rsum_ws);
    mean_kernel<<<dim3(16384), dim3(256), 0, stream>>>(p_ws, rsum_ws,
                                                       out + HOUT_OFF);
  } else {
    attn_kernel<<<dim3(256, 2), dim3(512), 0, stream>>>(
        Q_h, K_h, V_t, tau, (const uint2*)adjb, cw, O_h, out + HOUT_OFF);
  }
  oproj_kernel<<<dim3(128, 4), dim3(256), 0, stream>>>(O_h, Wo_h, bo, out);
}